// Round 8
// baseline (44.607 us; speedup 1.0000x reference)
//
#include <hip/hip_runtime.h>

// out[k] = sum_n sum_{i,j} frac[n,i]*frac[n,j]*cg[i,j,k]
//        = sum_{i,j} M[i][j] * cg[i,j,k],  M = sum_n x x^T (3x3 symmetric, 6 uniques)
//
// Single fused kernel, relaxed-agent-atomic last-block reduction:
//  - streaming body = R5 (best measured): lane owns 48 B = 3 consecutive float4
//    = 4 complete rows per segment, 4 segments x 3 loads = 12 dwordx4 straight-line.
//  - per-block 6 partials published via __hip_atomic_exchange(RELAXED, AGENT)
//    (RMW executes at LLC; NO wbL2 — R3's 131us came from ACQ_REL cache
//    maintenance per block, not from fusion itself).
//  - ordering: exchanges are acked (vmcnt drained) by __syncthreads() BEFORE
//    thread 0's relaxed fetch_add on the arrival counter -> at the LLC, every
//    block's partials precede its counter bump -> last block's relaxed atomic
//    loads see final values. Deterministic (fixed summation order).
//  - counter zeroed per call by 4 B hipMemsetAsync node (graph-capture-safe, R3).
// ws layout: ws[0] counter; partials at ws+8: [6][GRID]. 8+6*2032 floats = 48.8 KB.

constexpr int BLK  = 256;
constexpr int GRID = 2032;                  // 6*GRID+8 floats fits proven ws budget
constexpr int WPB  = BLK / 64;              // 4 waves per block
constexpr long NWAVES = (long)GRID * WPB;   // 8128
// chunk = 768 float4 = 3072 floats = 1024 rows = 12 KB per wave-iteration

#define ACC6(x, y, z)                                              \
    do {                                                           \
        s00 = fmaf((x), (x), s00); s01 = fmaf((x), (y), s01);      \
        s02 = fmaf((x), (z), s02); s11 = fmaf((y), (y), s11);      \
        s12 = fmaf((y), (z), s12); s22 = fmaf((z), (z), s22);      \
    } while (0)

__global__ __launch_bounds__(BLK) void tp_fused(const float* __restrict__ frac,
                                                float* __restrict__ ws,
                                                const float* __restrict__ cg,
                                                float* __restrict__ out,
                                                long nchunks, long tail_row,
                                                long nrows) {
    const int  lane = threadIdx.x & 63;
    const int  w    = threadIdx.x >> 6;
    const long wglb = (long)blockIdx.x * WPB + w;
    const float4* __restrict__ f4 = reinterpret_cast<const float4*>(frac);

    float* __restrict__ part = ws + 8;      // [6][GRID]
    unsigned* counter = reinterpret_cast<unsigned*>(ws);

    float s00 = 0.f, s01 = 0.f, s02 = 0.f, s11 = 0.f, s12 = 0.f, s22 = 0.f;

    for (long c = wglb; c < nchunks; c += NWAVES) {
        const long base = c * 768 + lane * 3;
        float4 v[12];
        #pragma unroll
        for (int s = 0; s < 4; ++s)
            #pragma unroll
            for (int k = 0; k < 3; ++k)
                v[s * 3 + k] = f4[base + 192 * s + k];   // 12 loads in flight

        #pragma unroll
        for (int s = 0; s < 4; ++s) {
            const float4 a = v[s * 3 + 0];
            const float4 b = v[s * 3 + 1];
            const float4 d = v[s * 3 + 2];
            ACC6(a.x, a.y, a.z);
            ACC6(a.w, b.x, b.y);
            ACC6(b.z, b.w, d.x);
            ACC6(d.y, d.z, d.w);
        }
    }

    // 64-lane butterfly reduction
    #pragma unroll
    for (int off = 32; off > 0; off >>= 1) {
        s00 += __shfl_down(s00, off);
        s01 += __shfl_down(s01, off);
        s02 += __shfl_down(s02, off);
        s11 += __shfl_down(s11, off);
        s12 += __shfl_down(s12, off);
        s22 += __shfl_down(s22, off);
    }

    __shared__ float red[WPB][6];
    __shared__ int   is_last;
    if (lane == 0) {
        red[w][0] = s00; red[w][1] = s01; red[w][2] = s02;
        red[w][3] = s11; red[w][4] = s12; red[w][5] = s22;
    }
    __syncthreads();

    // publish 6 partials via relaxed agent-scope RMW (executes at LLC, no wbL2)
    if (threadIdx.x < 6) {
        float v = red[0][threadIdx.x] + red[1][threadIdx.x]
                + red[2][threadIdx.x] + red[3][threadIdx.x];
        __hip_atomic_exchange(&part[threadIdx.x * GRID + blockIdx.x], v,
                              __ATOMIC_RELAXED, __HIP_MEMORY_SCOPE_AGENT);
    }
    __syncthreads();   // drains vmcnt: exchanges ACKED at LLC before any thread passes

    if (threadIdx.x == 0) {
        unsigned old = __hip_atomic_fetch_add(counter, 1u, __ATOMIC_RELAXED,
                                              __HIP_MEMORY_SCOPE_AGENT);
        is_last = (old == GRID - 1) ? 1 : 0;
    }
    __syncthreads();
    if (!is_last) return;

    // ---- last-arriving block: final reduction + tail + contraction ----
    float s[6] = {0.f, 0.f, 0.f, 0.f, 0.f, 0.f};
    for (int b = threadIdx.x; b < GRID; b += BLK) {
        #pragma unroll
        for (int c = 0; c < 6; ++c)
            s[c] += __hip_atomic_load(&part[c * GRID + b],
                                      __ATOMIC_RELAXED, __HIP_MEMORY_SCOPE_AGENT);
    }
    // generic row tail (none for N = 2^23)
    for (long r = tail_row + threadIdx.x; r < nrows; r += BLK) {
        float x = frac[3 * r + 0], y = frac[3 * r + 1], z = frac[3 * r + 2];
        s[0] = fmaf(x, x, s[0]); s[1] = fmaf(x, y, s[1]); s[2] = fmaf(x, z, s[2]);
        s[3] = fmaf(y, y, s[3]); s[4] = fmaf(y, z, s[4]); s[5] = fmaf(z, z, s[5]);
    }

    #pragma unroll
    for (int off = 32; off > 0; off >>= 1) {
        #pragma unroll
        for (int c = 0; c < 6; ++c) s[c] += __shfl_down(s[c], off);
    }
    if (lane == 0) {
        #pragma unroll
        for (int c = 0; c < 6; ++c) red[w][c] = s[c];
    }
    __syncthreads();

    __shared__ float fin[6 + 9];
    if (threadIdx.x < 6)
        fin[threadIdx.x] = red[0][threadIdx.x] + red[1][threadIdx.x]
                         + red[2][threadIdx.x] + red[3][threadIdx.x];
    __syncthreads();
    if (threadIdx.x == 0) {
        fin[6 + 0] = fin[0]; fin[6 + 1] = fin[1]; fin[6 + 2] = fin[2];
        fin[6 + 3] = fin[1]; fin[6 + 4] = fin[3]; fin[6 + 5] = fin[4];
        fin[6 + 6] = fin[2]; fin[6 + 7] = fin[4]; fin[6 + 8] = fin[5];
    }
    __syncthreads();
    if (threadIdx.x < 9) {
        const int k = threadIdx.x;
        float acc = 0.f;
        #pragma unroll
        for (int p = 0; p < 9; ++p)
            acc = fmaf(fin[6 + p], cg[p * 9 + k], acc);   // cg[(i*3+j)*9 + k]
        out[k] = acc;
    }
}

extern "C" void kernel_launch(void* const* d_in, const int* in_sizes, int n_in,
                              void* d_out, int out_size, void* d_ws, size_t ws_size,
                              hipStream_t stream) {
    const float* frac = (const float*)d_in[0];   // [N, 3] flat
    const float* cg   = (const float*)d_in[1];   // [3, 3, 9] flat
    float*       out  = (float*)d_out;           // [9]
    float*       ws   = (float*)d_ws;            // counter + 6*GRID partials

    const long nfloats  = in_sizes[0];           // 3*N
    const long nrows    = nfloats / 3;
    const long nchunks  = nfloats / 3072;        // 12 KB chunks (8192 for N=2^23)
    const long tail_row = nchunks * 1024;        // rows covered by streaming loop

    hipMemsetAsync(d_ws, 0, 4, stream);          // zero arrival counter
    tp_fused<<<GRID, BLK, 0, stream>>>(frac, ws, cg, out, nchunks, tail_row, nrows);
}

// Round 9
// 44.514 us; speedup vs baseline: 1.0021x; 1.0021x over previous
//
#include <hip/hip_runtime.h>

// out[k] = sum_n sum_{i,j} frac[n,i]*frac[n,j]*cg[i,j,k]
//        = sum_{i,j} M[i][j] * cg[i,j,k],  M = sum_n x x^T (3x3 symmetric, 6 uniques)
//
// Single kernel + 36B memset node. Streaming body = R5 (best measured, 22.9us):
//   lane owns 48 B = 3 consecutive float4 = 4 complete rows per segment,
//   4 segments x 3 loads = 12 dwordx4 straight-line, GRID=2048.
// Epilogue: each block contracts its OWN local M (6 uniques) with cg and does
//   9 NO-RETURN device-scope atomicAdds into out[9].
//   - no arrival counter (R8 post-mortem: 2K same-line RMWs serialize at LLC)
//   - no partial re-read (R8: scalar atomic loads on one CU = latency wall)
//   - no-return global_atomic_add_f32 pipelines at the LLC (fire-and-forget).
// d_out zeroed per call by hipMemsetAsync(36B) — graph-capture-safe (proven R3/R8).
// FP note: 2048-way atomic accumulation order varies per replay; noise ~1 ulp
// vs threshold 2.9e5 on values ~8e6 — well inside harness tolerance.

constexpr int BLK  = 256;
constexpr int GRID = 2048;
constexpr int WPB  = BLK / 64;              // 4 waves per block
constexpr long NWAVES = (long)GRID * WPB;   // 8192
// chunk = 768 float4 = 3072 floats = 1024 rows = 12 KB per wave-iteration

#define ACC6(x, y, z)                                              \
    do {                                                           \
        s00 = fmaf((x), (x), s00); s01 = fmaf((x), (y), s01);      \
        s02 = fmaf((x), (z), s02); s11 = fmaf((y), (y), s11);      \
        s12 = fmaf((y), (z), s12); s22 = fmaf((z), (z), s22);      \
    } while (0)

__global__ __launch_bounds__(BLK) void tp_fused(const float* __restrict__ frac,
                                                const float* __restrict__ cg,
                                                float* __restrict__ out,
                                                long nchunks, long tail_row,
                                                long nrows) {
    const int  lane = threadIdx.x & 63;
    const int  w    = threadIdx.x >> 6;
    const long wglb = (long)blockIdx.x * WPB + w;
    const float4* __restrict__ f4 = reinterpret_cast<const float4*>(frac);

    float s00 = 0.f, s01 = 0.f, s02 = 0.f, s11 = 0.f, s12 = 0.f, s22 = 0.f;

    for (long c = wglb; c < nchunks; c += NWAVES) {   // trip count 1 @ N=2^23
        const long base = c * 768 + lane * 3;
        float4 v[12];
        #pragma unroll
        for (int s = 0; s < 4; ++s)
            #pragma unroll
            for (int k = 0; k < 3; ++k)
                v[s * 3 + k] = f4[base + 192 * s + k];   // 12 loads in flight

        #pragma unroll
        for (int s = 0; s < 4; ++s) {
            const float4 a = v[s * 3 + 0];
            const float4 b = v[s * 3 + 1];
            const float4 d = v[s * 3 + 2];
            ACC6(a.x, a.y, a.z);
            ACC6(a.w, b.x, b.y);
            ACC6(b.z, b.w, d.x);
            ACC6(d.y, d.z, d.w);
        }
    }

    // generic row tail, handled by block 0 (none for N = 2^23)
    if (blockIdx.x == 0) {
        for (long r = tail_row + threadIdx.x; r < nrows; r += BLK) {
            float x = frac[3 * r + 0], y = frac[3 * r + 1], z = frac[3 * r + 2];
            ACC6(x, y, z);
        }
    }

    // 64-lane butterfly reduction
    #pragma unroll
    for (int off = 32; off > 0; off >>= 1) {
        s00 += __shfl_down(s00, off);
        s01 += __shfl_down(s01, off);
        s02 += __shfl_down(s02, off);
        s11 += __shfl_down(s11, off);
        s12 += __shfl_down(s12, off);
        s22 += __shfl_down(s22, off);
    }

    __shared__ float red[WPB][6];
    if (lane == 0) {
        red[w][0] = s00; red[w][1] = s01; red[w][2] = s02;
        red[w][3] = s11; red[w][4] = s12; red[w][5] = s22;
    }
    __syncthreads();

    __shared__ float M[9];   // this block's full 3x3
    if (threadIdx.x == 0) {
        float t[6];
        #pragma unroll
        for (int c = 0; c < 6; ++c)
            t[c] = red[0][c] + red[1][c] + red[2][c] + red[3][c];
        M[0] = t[0];  M[1] = t[1];  M[2] = t[2];
        M[3] = t[1];  M[4] = t[3];  M[5] = t[4];
        M[6] = t[2];  M[7] = t[4];  M[8] = t[5];
    }
    __syncthreads();

    // block's contribution to out[k]; no-return device-scope atomicAdd
    if (threadIdx.x < 9) {
        const int k = threadIdx.x;
        float acc = 0.f;
        #pragma unroll
        for (int p = 0; p < 9; ++p)
            acc = fmaf(M[p], cg[p * 9 + k], acc);   // cg[(i*3+j)*9 + k]
        atomicAdd(&out[k], acc);
    }
}

extern "C" void kernel_launch(void* const* d_in, const int* in_sizes, int n_in,
                              void* d_out, int out_size, void* d_ws, size_t ws_size,
                              hipStream_t stream) {
    const float* frac = (const float*)d_in[0];   // [N, 3] flat
    const float* cg   = (const float*)d_in[1];   // [3, 3, 9] flat
    float*       out  = (float*)d_out;           // [9]

    const long nfloats  = in_sizes[0];           // 3*N
    const long nrows    = nfloats / 3;
    const long nchunks  = nfloats / 3072;        // 12 KB chunks (8192 for N=2^23)
    const long tail_row = nchunks * 1024;        // rows covered by streaming loop

    hipMemsetAsync(d_out, 0, out_size * sizeof(float), stream);  // zero accumulators
    tp_fused<<<GRID, BLK, 0, stream>>>(frac, cg, out, nchunks, tail_row, nrows);
}

// Round 10
// 38.241 us; speedup vs baseline: 1.1665x; 1.1640x over previous
//
#include <hip/hip_runtime.h>

// MEASUREMENT PROBE (R10): R5's exact two-kernel structure, but tp_partial is
// launched TWICE (second launch rewrites byte-identical partials to the same
// ws -> idempotent, deterministic, output unchanged). Purpose: total_dur =
// 2*p1 + (pass2 + gaps)  =>  p1 ~= total - 22.9us. The rocprof top-5 is
// saturated by 57us harness fill kernels, so our sub-25us kernels never
// surface in counters; this is the only way to read the p1/p2 split.
//
// Decision rule (committed before measuring):
//   p1 >= 20us  -> pass-2 overhead minimal; pass-1 read path ~5 TB/s across 6
//                  structural variants = practical ceiling; revert to R5, test
//                  nontemporal loads, then declare.
//   p1 <= 17.5  -> pass-2+gap >= 5us; attack node 2 (fewer partials, wider block).
//
// R3/R8/R9 post-mortems: all single-kernel fusion shapes dead (~2048-deep
// same-address LLC atomic chains ~ 10ns/link ~ 20us; acq-rel adds wbL2 -> 131us).

constexpr int BLK  = 256;
constexpr int GRID = 2048;
constexpr int WPB  = BLK / 64;              // 4 waves per block
constexpr long NWAVES = (long)GRID * WPB;   // 8192
// chunk = 768 float4 = 3072 floats = 1024 rows = 12 KB per wave-iteration

#define ACC6(x, y, z)                                              \
    do {                                                           \
        s00 = fmaf((x), (x), s00); s01 = fmaf((x), (y), s01);      \
        s02 = fmaf((x), (z), s02); s11 = fmaf((y), (y), s11);      \
        s12 = fmaf((y), (z), s12); s22 = fmaf((z), (z), s22);      \
    } while (0)

__global__ __launch_bounds__(BLK) void tp_partial(const float* __restrict__ frac,
                                                  float* __restrict__ ws,
                                                  long nchunks) {
    const int  lane = threadIdx.x & 63;
    const int  w    = threadIdx.x >> 6;
    const long wglb = (long)blockIdx.x * WPB + w;
    const float4* __restrict__ f4 = reinterpret_cast<const float4*>(frac);

    float s00 = 0.f, s01 = 0.f, s02 = 0.f, s11 = 0.f, s12 = 0.f, s22 = 0.f;

    for (long c = wglb; c < nchunks; c += NWAVES) {   // trip count 1 @ N=2^23
        const long base = c * 768 + lane * 3;
        float4 v[12];
        #pragma unroll
        for (int s = 0; s < 4; ++s)
            #pragma unroll
            for (int k = 0; k < 3; ++k)
                v[s * 3 + k] = f4[base + 192 * s + k];   // 12 loads in flight

        #pragma unroll
        for (int s = 0; s < 4; ++s) {
            const float4 a = v[s * 3 + 0];
            const float4 b = v[s * 3 + 1];
            const float4 d = v[s * 3 + 2];
            ACC6(a.x, a.y, a.z);
            ACC6(a.w, b.x, b.y);
            ACC6(b.z, b.w, d.x);
            ACC6(d.y, d.z, d.w);
        }
    }

    // 64-lane butterfly reduction
    #pragma unroll
    for (int off = 32; off > 0; off >>= 1) {
        s00 += __shfl_down(s00, off);
        s01 += __shfl_down(s01, off);
        s02 += __shfl_down(s02, off);
        s11 += __shfl_down(s11, off);
        s12 += __shfl_down(s12, off);
        s22 += __shfl_down(s22, off);
    }

    __shared__ float red[WPB][6];
    if (lane == 0) {
        red[w][0] = s00; red[w][1] = s01; red[w][2] = s02;
        red[w][3] = s11; red[w][4] = s12; red[w][5] = s22;
    }
    __syncthreads();
    if (threadIdx.x < 6) {
        float v = red[0][threadIdx.x] + red[1][threadIdx.x]
                + red[2][threadIdx.x] + red[3][threadIdx.x];
        ws[threadIdx.x * GRID + blockIdx.x] = v;   // transposed [6][GRID]
    }
}

__global__ __launch_bounds__(BLK) void tp_final(const float* __restrict__ frac,
                                                const float* __restrict__ ws,
                                                const float* __restrict__ cg,
                                                float* __restrict__ out,
                                                long tail_row, long nrows) {
    const float4* __restrict__ w4 = reinterpret_cast<const float4*>(ws); // [6][GRID/4]
    constexpr int Q = GRID / 4;   // 512 float4 per component

    float s[6];
    #pragma unroll
    for (int c = 0; c < 6; ++c) {
        float4 a = w4[c * Q + threadIdx.x];
        float4 b = w4[c * Q + threadIdx.x + BLK];
        s[c] = ((a.x + a.y) + (a.z + a.w)) + ((b.x + b.y) + (b.z + b.w));
    }

    // generic row tail (none for N = 2^23)
    for (long r = tail_row + threadIdx.x; r < nrows; r += BLK) {
        float x = frac[3 * r + 0], y = frac[3 * r + 1], z = frac[3 * r + 2];
        s[0] = fmaf(x, x, s[0]); s[1] = fmaf(x, y, s[1]); s[2] = fmaf(x, z, s[2]);
        s[3] = fmaf(y, y, s[3]); s[4] = fmaf(y, z, s[4]); s[5] = fmaf(z, z, s[5]);
    }

    #pragma unroll
    for (int off = 32; off > 0; off >>= 1) {
        #pragma unroll
        for (int c = 0; c < 6; ++c) s[c] += __shfl_down(s[c], off);
    }

    __shared__ float red[BLK / 64][6];
    const int lane = threadIdx.x & 63;
    const int wave = threadIdx.x >> 6;
    if (lane == 0) {
        #pragma unroll
        for (int c = 0; c < 6; ++c) red[wave][c] = s[c];
    }
    __syncthreads();

    __shared__ float M[9];
    if (threadIdx.x == 0) {
        float t[6];
        #pragma unroll
        for (int c = 0; c < 6; ++c)
            t[c] = red[0][c] + red[1][c] + red[2][c] + red[3][c];
        M[0] = t[0];  M[1] = t[1];  M[2] = t[2];
        M[3] = t[1];  M[4] = t[3];  M[5] = t[4];
        M[6] = t[2];  M[7] = t[4];  M[8] = t[5];
    }
    __syncthreads();

    if (threadIdx.x < 9) {
        const int k = threadIdx.x;
        float acc = 0.f;
        #pragma unroll
        for (int p = 0; p < 9; ++p)
            acc = fmaf(M[p], cg[p * 9 + k], acc);   // cg[(i*3+j)*9 + k]
        out[k] = acc;
    }
}

extern "C" void kernel_launch(void* const* d_in, const int* in_sizes, int n_in,
                              void* d_out, int out_size, void* d_ws, size_t ws_size,
                              hipStream_t stream) {
    const float* frac = (const float*)d_in[0];   // [N, 3] flat
    const float* cg   = (const float*)d_in[1];   // [3, 3, 9] flat
    float*       out  = (float*)d_out;           // [9]
    float*       ws   = (float*)d_ws;            // 6*GRID floats = 48 KB

    const long nfloats  = in_sizes[0];           // 3*N
    const long nrows    = nfloats / 3;
    const long nchunks  = nfloats / 3072;        // 12 KB chunks (8192 for N=2^23)
    const long tail_row = nchunks * 1024;        // rows covered by pass 1

    // PROBE: run pass 1 twice (idempotent). total ~= 2*p1 + p2 + gaps.
    tp_partial<<<GRID, BLK, 0, stream>>>(frac, ws, nchunks);
    tp_partial<<<GRID, BLK, 0, stream>>>(frac, ws, nchunks);
    tp_final<<<1, BLK, 0, stream>>>(frac, ws, cg, out, tail_row, nrows);
}

// Round 11
// 27.517 us; speedup vs baseline: 1.6211x; 1.3897x over previous
//
#include <hip/hip_runtime.h>

// out[k] = sum_n sum_{i,j} frac[n,i]*frac[n,j]*cg[i,j,k]
//        = sum_{i,j} M[i][j] * cg[i,j,k],  M = sum_n x x^T (3x3 symmetric, 6 uniques)
//
// R10 probe decode: p1 ~= 15.3us (6.6-6.9 TB/s = read ceiling, matches fill
// kernels), p2_total ~= 7.6us for a 48KB 1-block kernel -> latency-bound on
// dirty-remote-L2 lines + too few waves. This round attacks ONLY pass 2:
//  - pass 1 partial stores are NONTEMPORAL (not dirty in writer's XCD L2,
//    so pass-2 reads are clean LLC hits instead of remote-dirty fetches)
//  - tp_final: 512 threads (8 waves), 6 independent float4 loads per thread
//    issued up-front (2x outstanding misses vs 4-wave version)
// Streaming body byte-identical to R5 (proven best, 22.9us total).
//
// R3/R8/R9 post-mortems: all single-kernel fusion shapes dead (same-address
// LLC atomic chains ~10ns/link; acq-rel adds per-block wbL2 -> 131us).

constexpr int BLK  = 256;
constexpr int GRID = 2048;
constexpr int WPB  = BLK / 64;              // 4 waves per block
constexpr long NWAVES = (long)GRID * WPB;   // 8192
// chunk = 768 float4 = 3072 floats = 1024 rows = 12 KB per wave-iteration

constexpr int BLK2 = 512;                   // tp_final: 8 waves

#define ACC6(x, y, z)                                              \
    do {                                                           \
        s00 = fmaf((x), (x), s00); s01 = fmaf((x), (y), s01);      \
        s02 = fmaf((x), (z), s02); s11 = fmaf((y), (y), s11);      \
        s12 = fmaf((y), (z), s12); s22 = fmaf((z), (z), s22);      \
    } while (0)

__global__ __launch_bounds__(BLK) void tp_partial(const float* __restrict__ frac,
                                                  float* __restrict__ ws,
                                                  long nchunks) {
    const int  lane = threadIdx.x & 63;
    const int  w    = threadIdx.x >> 6;
    const long wglb = (long)blockIdx.x * WPB + w;
    const float4* __restrict__ f4 = reinterpret_cast<const float4*>(frac);

    float s00 = 0.f, s01 = 0.f, s02 = 0.f, s11 = 0.f, s12 = 0.f, s22 = 0.f;

    for (long c = wglb; c < nchunks; c += NWAVES) {   // trip count 1 @ N=2^23
        const long base = c * 768 + lane * 3;
        float4 v[12];
        #pragma unroll
        for (int s = 0; s < 4; ++s)
            #pragma unroll
            for (int k = 0; k < 3; ++k)
                v[s * 3 + k] = f4[base + 192 * s + k];   // 12 loads in flight

        #pragma unroll
        for (int s = 0; s < 4; ++s) {
            const float4 a = v[s * 3 + 0];
            const float4 b = v[s * 3 + 1];
            const float4 d = v[s * 3 + 2];
            ACC6(a.x, a.y, a.z);
            ACC6(a.w, b.x, b.y);
            ACC6(b.z, b.w, d.x);
            ACC6(d.y, d.z, d.w);
        }
    }

    // 64-lane butterfly reduction
    #pragma unroll
    for (int off = 32; off > 0; off >>= 1) {
        s00 += __shfl_down(s00, off);
        s01 += __shfl_down(s01, off);
        s02 += __shfl_down(s02, off);
        s11 += __shfl_down(s11, off);
        s12 += __shfl_down(s12, off);
        s22 += __shfl_down(s22, off);
    }

    __shared__ float red[WPB][6];
    if (lane == 0) {
        red[w][0] = s00; red[w][1] = s01; red[w][2] = s02;
        red[w][3] = s11; red[w][4] = s12; red[w][5] = s22;
    }
    __syncthreads();
    if (threadIdx.x < 6) {
        float v = red[0][threadIdx.x] + red[1][threadIdx.x]
                + red[2][threadIdx.x] + red[3][threadIdx.x];
        // nontemporal: don't leave the line dirty in this XCD's L2 —
        // pass 2 then reads a clean LLC line instead of a remote-dirty fetch
        __builtin_nontemporal_store(v, &ws[threadIdx.x * GRID + blockIdx.x]);
    }
}

__global__ __launch_bounds__(BLK2) void tp_final(const float* __restrict__ frac,
                                                 const float* __restrict__ ws,
                                                 const float* __restrict__ cg,
                                                 float* __restrict__ out,
                                                 long tail_row, long nrows) {
    const float4* __restrict__ w4 = reinterpret_cast<const float4*>(ws); // [6][GRID/4]
    constexpr int Q = GRID / 4;   // 512 float4 per component = BLK2

    // all 6 loads issued before any use: 6 outstanding misses per thread
    float4 a[6];
    #pragma unroll
    for (int c = 0; c < 6; ++c)
        a[c] = w4[c * Q + threadIdx.x];

    float s[6];
    #pragma unroll
    for (int c = 0; c < 6; ++c)
        s[c] = (a[c].x + a[c].y) + (a[c].z + a[c].w);

    // generic row tail (none for N = 2^23)
    for (long r = tail_row + threadIdx.x; r < nrows; r += BLK2) {
        float x = frac[3 * r + 0], y = frac[3 * r + 1], z = frac[3 * r + 2];
        s[0] = fmaf(x, x, s[0]); s[1] = fmaf(x, y, s[1]); s[2] = fmaf(x, z, s[2]);
        s[3] = fmaf(y, y, s[3]); s[4] = fmaf(y, z, s[4]); s[5] = fmaf(z, z, s[5]);
    }

    #pragma unroll
    for (int off = 32; off > 0; off >>= 1) {
        #pragma unroll
        for (int c = 0; c < 6; ++c) s[c] += __shfl_down(s[c], off);
    }

    __shared__ float red[BLK2 / 64][6];   // 8 waves
    const int lane = threadIdx.x & 63;
    const int wave = threadIdx.x >> 6;
    if (lane == 0) {
        #pragma unroll
        for (int c = 0; c < 6; ++c) red[wave][c] = s[c];
    }
    __syncthreads();

    __shared__ float M[9];
    if (threadIdx.x == 0) {
        float t[6];
        #pragma unroll
        for (int c = 0; c < 6; ++c) {
            float v = 0.f;
            #pragma unroll
            for (int wv = 0; wv < BLK2 / 64; ++wv) v += red[wv][c];
            t[c] = v;
        }
        M[0] = t[0];  M[1] = t[1];  M[2] = t[2];
        M[3] = t[1];  M[4] = t[3];  M[5] = t[4];
        M[6] = t[2];  M[7] = t[4];  M[8] = t[5];
    }
    __syncthreads();

    if (threadIdx.x < 9) {
        const int k = threadIdx.x;
        float acc = 0.f;
        #pragma unroll
        for (int p = 0; p < 9; ++p)
            acc = fmaf(M[p], cg[p * 9 + k], acc);   // cg[(i*3+j)*9 + k]
        out[k] = acc;
    }
}

extern "C" void kernel_launch(void* const* d_in, const int* in_sizes, int n_in,
                              void* d_out, int out_size, void* d_ws, size_t ws_size,
                              hipStream_t stream) {
    const float* frac = (const float*)d_in[0];   // [N, 3] flat
    const float* cg   = (const float*)d_in[1];   // [3, 3, 9] flat
    float*       out  = (float*)d_out;           // [9]
    float*       ws   = (float*)d_ws;            // 6*GRID floats = 48 KB

    const long nfloats  = in_sizes[0];           // 3*N
    const long nrows    = nfloats / 3;
    const long nchunks  = nfloats / 3072;        // 12 KB chunks (8192 for N=2^23)
    const long tail_row = nchunks * 1024;        // rows covered by pass 1

    tp_partial<<<GRID, BLK, 0, stream>>>(frac, ws, nchunks);
    tp_final<<<1, BLK2, 0, stream>>>(frac, ws, cg, out, tail_row, nrows);
}

// Round 12
// 23.440 us; speedup vs baseline: 1.9030x; 1.1739x over previous
//
#include <hip/hip_runtime.h>

// out[k] = sum_n sum_{i,j} frac[n,i]*frac[n,j]*cg[i,j,k]
//        = sum_{i,j} M[i][j] * cg[i,j,k],  M = sum_n x x^T (3x3 symmetric, 6 uniques)
//
// R12 = clean A/B: R5's exact pass-1 (plain stores — R11's nontemporal store
// pushed partials toward HBM and cost +4.6us) + R11's 8-wave upfront-load
// final (512 thr, 6 independent coalesced dwordx4 before any use).
// R10 probe: p1 ~= 15.3us (6.6-6.9 TB/s = read ceiling, matches harness
// fills); R5's p2+gap = 7.6us is the only remaining target.
//
// R3/R8/R9: all single-kernel fusion shapes dead (same-address LLC atomic
// chains ~10ns/link; acq-rel adds per-block wbL2 -> 131us).

constexpr int BLK  = 256;
constexpr int GRID = 2048;
constexpr int WPB  = BLK / 64;              // 4 waves per block
constexpr long NWAVES = (long)GRID * WPB;   // 8192
// chunk = 768 float4 = 3072 floats = 1024 rows = 12 KB per wave-iteration

constexpr int BLK2 = 512;                   // tp_final: 8 waves

#define ACC6(x, y, z)                                              \
    do {                                                           \
        s00 = fmaf((x), (x), s00); s01 = fmaf((x), (y), s01);      \
        s02 = fmaf((x), (z), s02); s11 = fmaf((y), (y), s11);      \
        s12 = fmaf((y), (z), s12); s22 = fmaf((z), (z), s22);      \
    } while (0)

__global__ __launch_bounds__(BLK) void tp_partial(const float* __restrict__ frac,
                                                  float* __restrict__ ws,
                                                  long nchunks) {
    const int  lane = threadIdx.x & 63;
    const int  w    = threadIdx.x >> 6;
    const long wglb = (long)blockIdx.x * WPB + w;
    const float4* __restrict__ f4 = reinterpret_cast<const float4*>(frac);

    float s00 = 0.f, s01 = 0.f, s02 = 0.f, s11 = 0.f, s12 = 0.f, s22 = 0.f;

    for (long c = wglb; c < nchunks; c += NWAVES) {   // trip count 1 @ N=2^23
        const long base = c * 768 + lane * 3;
        float4 v[12];
        #pragma unroll
        for (int s = 0; s < 4; ++s)
            #pragma unroll
            for (int k = 0; k < 3; ++k)
                v[s * 3 + k] = f4[base + 192 * s + k];   // 12 loads in flight

        #pragma unroll
        for (int s = 0; s < 4; ++s) {
            const float4 a = v[s * 3 + 0];
            const float4 b = v[s * 3 + 1];
            const float4 d = v[s * 3 + 2];
            ACC6(a.x, a.y, a.z);
            ACC6(a.w, b.x, b.y);
            ACC6(b.z, b.w, d.x);
            ACC6(d.y, d.z, d.w);
        }
    }

    // 64-lane butterfly reduction
    #pragma unroll
    for (int off = 32; off > 0; off >>= 1) {
        s00 += __shfl_down(s00, off);
        s01 += __shfl_down(s01, off);
        s02 += __shfl_down(s02, off);
        s11 += __shfl_down(s11, off);
        s12 += __shfl_down(s12, off);
        s22 += __shfl_down(s22, off);
    }

    __shared__ float red[WPB][6];
    if (lane == 0) {
        red[w][0] = s00; red[w][1] = s01; red[w][2] = s02;
        red[w][3] = s11; red[w][4] = s12; red[w][5] = s22;
    }
    __syncthreads();
    if (threadIdx.x < 6) {
        float v = red[0][threadIdx.x] + red[1][threadIdx.x]
                + red[2][threadIdx.x] + red[3][threadIdx.x];
        ws[threadIdx.x * GRID + blockIdx.x] = v;   // transposed [6][GRID], plain store
    }
}

__global__ __launch_bounds__(BLK2) void tp_final(const float* __restrict__ frac,
                                                 const float* __restrict__ ws,
                                                 const float* __restrict__ cg,
                                                 float* __restrict__ out,
                                                 long tail_row, long nrows) {
    const float4* __restrict__ w4 = reinterpret_cast<const float4*>(ws); // [6][GRID/4]
    constexpr int Q = GRID / 4;   // 512 float4 per component = BLK2

    // all 6 loads issued before any use: 6 outstanding misses per thread
    float4 a[6];
    #pragma unroll
    for (int c = 0; c < 6; ++c)
        a[c] = w4[c * Q + threadIdx.x];

    float s[6];
    #pragma unroll
    for (int c = 0; c < 6; ++c)
        s[c] = (a[c].x + a[c].y) + (a[c].z + a[c].w);

    // generic row tail (none for N = 2^23)
    for (long r = tail_row + threadIdx.x; r < nrows; r += BLK2) {
        float x = frac[3 * r + 0], y = frac[3 * r + 1], z = frac[3 * r + 2];
        s[0] = fmaf(x, x, s[0]); s[1] = fmaf(x, y, s[1]); s[2] = fmaf(x, z, s[2]);
        s[3] = fmaf(y, y, s[3]); s[4] = fmaf(y, z, s[4]); s[5] = fmaf(z, z, s[5]);
    }

    #pragma unroll
    for (int off = 32; off > 0; off >>= 1) {
        #pragma unroll
        for (int c = 0; c < 6; ++c) s[c] += __shfl_down(s[c], off);
    }

    __shared__ float red[BLK2 / 64][6];   // 8 waves
    const int lane = threadIdx.x & 63;
    const int wave = threadIdx.x >> 6;
    if (lane == 0) {
        #pragma unroll
        for (int c = 0; c < 6; ++c) red[wave][c] = s[c];
    }
    __syncthreads();

    __shared__ float M[9];
    if (threadIdx.x == 0) {
        float t[6];
        #pragma unroll
        for (int c = 0; c < 6; ++c) {
            float v = 0.f;
            #pragma unroll
            for (int wv = 0; wv < BLK2 / 64; ++wv) v += red[wv][c];
            t[c] = v;
        }
        M[0] = t[0];  M[1] = t[1];  M[2] = t[2];
        M[3] = t[1];  M[4] = t[3];  M[5] = t[4];
        M[6] = t[2];  M[7] = t[4];  M[8] = t[5];
    }
    __syncthreads();

    if (threadIdx.x < 9) {
        const int k = threadIdx.x;
        float acc = 0.f;
        #pragma unroll
        for (int p = 0; p < 9; ++p)
            acc = fmaf(M[p], cg[p * 9 + k], acc);   // cg[(i*3+j)*9 + k]
        out[k] = acc;
    }
}

extern "C" void kernel_launch(void* const* d_in, const int* in_sizes, int n_in,
                              void* d_out, int out_size, void* d_ws, size_t ws_size,
                              hipStream_t stream) {
    const float* frac = (const float*)d_in[0];   // [N, 3] flat
    const float* cg   = (const float*)d_in[1];   // [3, 3, 9] flat
    float*       out  = (float*)d_out;           // [9]
    float*       ws   = (float*)d_ws;            // 6*GRID floats = 48 KB

    const long nfloats  = in_sizes[0];           // 3*N
    const long nrows    = nfloats / 3;
    const long nchunks  = nfloats / 3072;        // 12 KB chunks (8192 for N=2^23)
    const long tail_row = nchunks * 1024;        // rows covered by pass 1

    tp_partial<<<GRID, BLK, 0, stream>>>(frac, ws, nchunks);
    tp_final<<<1, BLK2, 0, stream>>>(frac, ws, cg, out, tail_row, nrows);
}

// Round 13
// 23.026 us; speedup vs baseline: 1.9372x; 1.0180x over previous
//
#include <hip/hip_runtime.h>

// FINAL (revert to R5 = best measured, 22.94us).
// out[k] = sum_n sum_{i,j} frac[n,i]*frac[n,j]*cg[i,j,k]
//        = sum_{i,j} M[i][j] * cg[i,j,k],  M = sum_n x x^T (3x3 symmetric, 6 uniques)
//
// Structure: two stream-ordered kernels.
//  Pass 1 (15.3us, measured by R10 double-launch probe = 96MB at ~6.8 TB/s,
//    within a few % of the 7.0 TB/s harness fill kernels = read ceiling):
//    wave owns a 12KB chunk; lane owns 48B = 3 consecutive float4 = 4 complete
//    rows per segment; 4 segments x 3 loads = 12 dwordx4 straight-line.
//  Pass 2 (~7.6us incl. node gap — FIXED overhead: R12's 8-wave/upfront-load
//    variant changed nothing; R11's NT store regressed +4.6us):
//    1 block, coalesced float4 reads of transposed partials, cg contract.
//
// Measured dead ends (do not revisit):
//  - fusion via acq-rel flag: per-block wbL2+inv -> 131us (R3)
//  - fusion via relaxed counter + last-block re-read: LLC RMW chain -> 44.6us (R8)
//  - fusion via direct atomicAdd(out[9]) fan-in: same chain -> 44.5us (R9)
//  - nontemporal partial stores: push to HBM, pass-2 pays -> +4.6us (R11)
//  - GRID=1024 co-residency (R6: +1.4us), dense+shfl stitching (R7: +0.6us),
//    dense+overlap loads (R4: +2.9us).

constexpr int BLK  = 256;
constexpr int GRID = 2048;
constexpr int WPB  = BLK / 64;              // 4 waves per block
constexpr long NWAVES = (long)GRID * WPB;   // 8192
// chunk = 768 float4 = 3072 floats = 1024 rows = 12 KB per wave-iteration

#define ACC6(x, y, z)                                              \
    do {                                                           \
        s00 = fmaf((x), (x), s00); s01 = fmaf((x), (y), s01);      \
        s02 = fmaf((x), (z), s02); s11 = fmaf((y), (y), s11);      \
        s12 = fmaf((y), (z), s12); s22 = fmaf((z), (z), s22);      \
    } while (0)

__global__ __launch_bounds__(BLK) void tp_partial(const float* __restrict__ frac,
                                                  float* __restrict__ ws,
                                                  long nchunks) {
    const int  lane = threadIdx.x & 63;
    const int  w    = threadIdx.x >> 6;
    const long wglb = (long)blockIdx.x * WPB + w;
    const float4* __restrict__ f4 = reinterpret_cast<const float4*>(frac);

    float s00 = 0.f, s01 = 0.f, s02 = 0.f, s11 = 0.f, s12 = 0.f, s22 = 0.f;

    for (long c = wglb; c < nchunks; c += NWAVES) {   // trip count 1 @ N=2^23
        const long base = c * 768 + lane * 3;
        float4 v[12];
        #pragma unroll
        for (int s = 0; s < 4; ++s)
            #pragma unroll
            for (int k = 0; k < 3; ++k)
                v[s * 3 + k] = f4[base + 192 * s + k];   // 12 loads in flight

        #pragma unroll
        for (int s = 0; s < 4; ++s) {
            const float4 a = v[s * 3 + 0];
            const float4 b = v[s * 3 + 1];
            const float4 d = v[s * 3 + 2];
            ACC6(a.x, a.y, a.z);
            ACC6(a.w, b.x, b.y);
            ACC6(b.z, b.w, d.x);
            ACC6(d.y, d.z, d.w);
        }
    }

    // 64-lane butterfly reduction
    #pragma unroll
    for (int off = 32; off > 0; off >>= 1) {
        s00 += __shfl_down(s00, off);
        s01 += __shfl_down(s01, off);
        s02 += __shfl_down(s02, off);
        s11 += __shfl_down(s11, off);
        s12 += __shfl_down(s12, off);
        s22 += __shfl_down(s22, off);
    }

    __shared__ float red[WPB][6];
    if (lane == 0) {
        red[w][0] = s00; red[w][1] = s01; red[w][2] = s02;
        red[w][3] = s11; red[w][4] = s12; red[w][5] = s22;
    }
    __syncthreads();
    if (threadIdx.x < 6) {
        float v = red[0][threadIdx.x] + red[1][threadIdx.x]
                + red[2][threadIdx.x] + red[3][threadIdx.x];
        ws[threadIdx.x * GRID + blockIdx.x] = v;   // transposed [6][GRID]
    }
}

__global__ __launch_bounds__(BLK) void tp_final(const float* __restrict__ frac,
                                                const float* __restrict__ ws,
                                                const float* __restrict__ cg,
                                                float* __restrict__ out,
                                                long tail_row, long nrows) {
    const float4* __restrict__ w4 = reinterpret_cast<const float4*>(ws); // [6][GRID/4]
    constexpr int Q = GRID / 4;   // 512 float4 per component

    float s[6];
    #pragma unroll
    for (int c = 0; c < 6; ++c) {
        float4 a = w4[c * Q + threadIdx.x];
        float4 b = w4[c * Q + threadIdx.x + BLK];
        s[c] = ((a.x + a.y) + (a.z + a.w)) + ((b.x + b.y) + (b.z + b.w));
    }

    // generic row tail (none for N = 2^23)
    for (long r = tail_row + threadIdx.x; r < nrows; r += BLK) {
        float x = frac[3 * r + 0], y = frac[3 * r + 1], z = frac[3 * r + 2];
        s[0] = fmaf(x, x, s[0]); s[1] = fmaf(x, y, s[1]); s[2] = fmaf(x, z, s[2]);
        s[3] = fmaf(y, y, s[3]); s[4] = fmaf(y, z, s[4]); s[5] = fmaf(z, z, s[5]);
    }

    #pragma unroll
    for (int off = 32; off > 0; off >>= 1) {
        #pragma unroll
        for (int c = 0; c < 6; ++c) s[c] += __shfl_down(s[c], off);
    }

    __shared__ float red[BLK / 64][6];
    const int lane = threadIdx.x & 63;
    const int wave = threadIdx.x >> 6;
    if (lane == 0) {
        #pragma unroll
        for (int c = 0; c < 6; ++c) red[wave][c] = s[c];
    }
    __syncthreads();

    __shared__ float M[9];
    if (threadIdx.x == 0) {
        float t[6];
        #pragma unroll
        for (int c = 0; c < 6; ++c)
            t[c] = red[0][c] + red[1][c] + red[2][c] + red[3][c];
        M[0] = t[0];  M[1] = t[1];  M[2] = t[2];
        M[3] = t[1];  M[4] = t[3];  M[5] = t[4];
        M[6] = t[2];  M[7] = t[4];  M[8] = t[5];
    }
    __syncthreads();

    if (threadIdx.x < 9) {
        const int k = threadIdx.x;
        float acc = 0.f;
        #pragma unroll
        for (int p = 0; p < 9; ++p)
            acc = fmaf(M[p], cg[p * 9 + k], acc);   // cg[(i*3+j)*9 + k]
        out[k] = acc;
    }
}

extern "C" void kernel_launch(void* const* d_in, const int* in_sizes, int n_in,
                              void* d_out, int out_size, void* d_ws, size_t ws_size,
                              hipStream_t stream) {
    const float* frac = (const float*)d_in[0];   // [N, 3] flat
    const float* cg   = (const float*)d_in[1];   // [3, 3, 9] flat
    float*       out  = (float*)d_out;           // [9]
    float*       ws   = (float*)d_ws;            // 6*GRID floats = 48 KB

    const long nfloats  = in_sizes[0];           // 3*N
    const long nrows    = nfloats / 3;
    const long nchunks  = nfloats / 3072;        // 12 KB chunks (8192 for N=2^23)
    const long tail_row = nchunks * 1024;        // rows covered by pass 1

    tp_partial<<<GRID, BLK, 0, stream>>>(frac, ws, nchunks);
    tp_final<<<1, BLK, 0, stream>>>(frac, ws, cg, out, tail_row, nrows);
}